// Round 7
// baseline (247.245 us; speedup 1.0000x reference)
//
#include <hip/hip_runtime.h>

#define NOUT 7
#define NROI 512
#define NCH 256
#define BINS (NOUT * NOUT)          // 49
#define ROI_ELEMS (NCH * BINS)      // 12544
#define CHB 8                       // channels per block
#define NCG (NCH / CHB)             // 32 channel-groups per roi
#define OUTS (CHB * BINS)           // 392 outputs per block
// Worst-case footprint: level selection bounds feature-area fw*fh < 784 with
// fw,fh <= 124; discrete max of rs*(cs|1) over that set is 1062 floats
// (fh=124, fw=6.3 skew). 1088 > 1062 is provably sufficient. (R2-verified.)
#define TILE_STRIDE 1088
#define NIT ((TILE_STRIDE + 255) / 256)   // 5 staging issues per channel

__global__ __launch_bounds__(256) void roi_pool_kernel(
    const float* __restrict__ x2,
    const float* __restrict__ x3,
    const float* __restrict__ x4,
    const float* __restrict__ x5,
    const float* __restrict__ boxes,
    float* __restrict__ out)
{
    const int r  = blockIdx.x;   // roi 0..511
    const int cg = blockIdx.y;   // channel group 0..31
    const int t  = threadIdx.x;  // 0..255

    // per-channel compact footprint tiles (runtime stride forced odd -> no
    // row-stride bank aliasing on the ds_read taps)
    __shared__ float tile[CHB][TILE_STRIDE];
    // per-ph: sdyA = {asint(rowoff_a), asint(rowoff_b), 0.25*va*(1-fya), 0.25*va*fya}
    //         sdyB = {0.25*vb*(1-fyb), 0.25*vb*fyb}   (rowoff = (i0 - ylo)*stride)
    // per-pw: sdxA = {asint(coloff_a), asint(coloff_b), va*(1-fxa), va*fxa}
    //         sdxB = {vb*(1-fxb), vb*fxb}             (coloff = i0 - xlo)
    __shared__ float4 sdyA[NOUT];
    __shared__ float2 sdyB[NOUT];
    __shared__ float4 sdxA[NOUT];
    __shared__ float2 sdxB[NOUT];
    __shared__ const float* s_src;  // feat + (b*NCH + cg*CHB)*HW + ylo*W + xlo
    __shared__ int s_W, s_HW, s_st, s_cs, s_pad;
    __shared__ unsigned s_M;        // ceil(2^32 / stride) for e -> row decomposition

    if (t < 32) {
        const float bx1 = boxes[4 * r + 0];
        const float by1 = boxes[4 * r + 1];
        const float bx2 = boxes[4 * r + 2];
        const float by2 = boxes[4 * r + 3];
        const float sz  = sqrtf((bx2 - bx1) * (by2 - by1));
        float lvlf = floorf(4.0f + log2f(sz / 224.0f + 1e-8f));
        lvlf = fminf(fmaxf(lvlf, 2.0f), 5.0f);
        const int level = (int)lvlf - 2;

        int H, W; float scale; const float* feat;
        if (level == 0)      { H = 200; W = 304; scale = 0.25f;    feat = x2; }
        else if (level == 1) { H = 100; W = 152; scale = 0.125f;   feat = x3; }
        else if (level == 2) { H = 50;  W = 76;  scale = 0.0625f;  feat = x4; }
        else                 { H = 25;  W = 38;  scale = 0.03125f; feat = x5; }

        const float X1 = bx1 * scale - 0.5f;
        const float Y1 = by1 * scale - 0.5f;
        const float X2 = bx2 * scale - 0.5f;
        const float Y2 = by2 * scale - 0.5f;
        const float bw = (X2 - X1) * (1.0f / NOUT);
        const float bh = (Y2 - Y1) * (1.0f / NOUT);

        // lanes 0..6: y-descriptors for ph = t; lanes 8..14: x-descriptors for
        // pw = t-8. All 32 lanes compute so the __shfl sources are valid.
        const bool isy = (t < 8);
        const int p    = min(isy ? t : (t - 8), 6);
        const int dim  = isy ? H : W;
        const float o0  = isy ? Y1 : X1;
        const float bsz = isy ? bh : bw;
        float ca = o0 + ((float)p + 0.25f) * bsz;
        float cb = o0 + ((float)p + 0.75f) * bsz;
        const float va = ((ca >= -1.0f) && (ca <= (float)dim)) ? 1.0f : 0.0f;
        const float vb = ((cb >= -1.0f) && (cb <= (float)dim)) ? 1.0f : 0.0f;
        ca = fminf(fmaxf(ca, 0.0f), (float)(dim - 1));
        cb = fminf(fmaxf(cb, 0.0f), (float)(dim - 1));
        const int ia = min((int)floorf(ca), dim - 2);   // taps ia, ia+1
        const int ib = min((int)floorf(cb), dim - 2);
        const float fa = ca - (float)ia;
        const float fb = cb - (float)ib;

        // footprint extents (sample positions are monotonic in p)
        const int ylo = __shfl(ia, 0);
        const int yhi = __shfl(ib, 6);
        const int xlo = __shfl(ia, 8);
        const int xhi = __shfl(ib, 14);
        const int cs = xhi + 2 - xlo;   // cols incl. +1 tap
        const int rs = yhi + 2 - ylo;   // rows incl. +1 tap
        const int st = cs | 1;          // odd LDS stride

        if (isy && t < 7) {
            sdyA[p] = make_float4(__int_as_float((ia - ylo) * st),
                                  __int_as_float((ib - ylo) * st),
                                  0.25f * va * (1.0f - fa), 0.25f * va * fa);
            sdyB[p] = make_float2(0.25f * vb * (1.0f - fb), 0.25f * vb * fb);
        } else if (!isy && t < 15) {
            sdxA[p] = make_float4(__int_as_float(ia - xlo),
                                  __int_as_float(ib - xlo),
                                  va * (1.0f - fa), va * fa);
            sdxB[p] = make_float2(vb * (1.0f - fb), vb * fb);
        } else if (t == 31) {
            const int HW = H * W;
            s_W   = W;
            s_HW  = HW;
            s_st  = st;
            s_cs  = cs;
            s_pad = min(rs * st, TILE_STRIDE);  // bound proven: rs*st <= 1062
            s_M   = (unsigned)(((1ull << 32) + (unsigned)st - 1) / (unsigned)st);
            s_src = feat + ((size_t)(r >> 8) * NCH + (size_t)cg * CHB) * HW
                         + (size_t)ylo * W + xlo;
        }
    }
    __syncthreads();

    // ---- stage: async global->LDS (fire-and-forget), one drain at barrier ----
    // R2's serial load->ds_write chain (27 dependent round-trips/lane ~= 10us
    // per block critical path) is replaced by 40 unrolled global_load_lds
    // issues, all in flight simultaneously. LDS dest is wave-uniform base +
    // lane*4 (t&192 = wave base within the block); global src is per-lane.
    {
        const int W   = s_W;
        const int st  = s_st;
        const int cs  = s_cs;
        const int pad = s_pad;
        const unsigned M = s_M;
        const int HW  = s_HW;
        const float* gsrc0 = s_src;
        const int wbase = t & 192;          // wave-uniform (0,64,128,192)
        const int lde   = t;                // lane's element slot = ebase + t
        #pragma unroll
        for (int ch = 0; ch < CHB; ++ch) {
            const float* gsrc = gsrc0 + (size_t)ch * HW;
            #pragma unroll
            for (int it = 0; it < NIT; ++it) {
                const int ebase = it * 256;
                const int e   = ebase + lde;
                const int row = (int)__umulhi((unsigned)e, M);  // e / st
                const int col = e - row * st;
                // col==cs only on the odd-pad column; never read -> skip
                // (stale LDS there is harmless). e>=pad slots never read.
                if (e < pad && col < cs) {
                    __builtin_amdgcn_global_load_lds(
                        (const __attribute__((address_space(1))) void*)
                            (gsrc + row * W + col),
                        (__attribute__((address_space(3))) void*)
                            (&tile[ch][ebase + wbase]),
                        4, 0, 0);
                }
            }
        }
    }
    __syncthreads();   // compiler emits vmcnt(0) drain before the barrier

    // ---- compute: 392 outputs per block from LDS (R2-verified) ----
    const int st = s_st;
    float* const obase = out + (size_t)r * ROI_ELEMS + (size_t)cg * OUTS;
    for (int o = t; o < OUTS; o += 256) {
        const int cl  = o / BINS;
        const int bin = o - cl * BINS;
        const int ph  = bin / NOUT;
        const int pw  = bin - ph * NOUT;

        const float4 yA = sdyA[ph];
        const float2 yB = sdyB[ph];
        const float4 xA = sdxA[pw];
        const float2 xB = sdxB[pw];
        const int ro0 = __float_as_int(yA.x);
        const int ro1 = __float_as_int(yA.y);
        const int co0 = __float_as_int(xA.x);
        const int co1 = __float_as_int(xA.y);

        const float* Ta = tile[cl] + ro0;   // row iya       (+st -> iya+1)
        const float* Tb = tile[cl] + ro1;   // row iyb       (+st -> iyb+1)
        const float d0 = Ta[co0] * xA.z + Ta[co0 + 1] * xA.w
                       + Ta[co1] * xB.x + Ta[co1 + 1] * xB.y;
        const float d1 = Ta[st + co0] * xA.z + Ta[st + co0 + 1] * xA.w
                       + Ta[st + co1] * xB.x + Ta[st + co1 + 1] * xB.y;
        const float d2 = Tb[co0] * xA.z + Tb[co0 + 1] * xA.w
                       + Tb[co1] * xB.x + Tb[co1 + 1] * xB.y;
        const float d3 = Tb[st + co0] * xA.z + Tb[st + co0 + 1] * xA.w
                       + Tb[st + co1] * xB.x + Tb[st + co1 + 1] * xB.y;

        obase[o] = yA.z * d0 + yA.w * d1 + yB.x * d2 + yB.y * d3;
    }
}

extern "C" void kernel_launch(void* const* d_in, const int* in_sizes, int n_in,
                              void* d_out, int out_size, void* d_ws, size_t ws_size,
                              hipStream_t stream) {
    const float* x2    = (const float*)d_in[0];
    const float* x3    = (const float*)d_in[1];
    const float* x4    = (const float*)d_in[2];
    const float* x5    = (const float*)d_in[3];
    const float* boxes = (const float*)d_in[4];
    float* out = (float*)d_out;

    dim3 grid(NROI, NCG);
    roi_pool_kernel<<<grid, 256, 0, stream>>>(x2, x3, x4, x5, boxes, out);
}

// Round 8
// 239.201 us; speedup vs baseline: 1.0336x; 1.0336x over previous
//
#include <hip/hip_runtime.h>

#define NOUT 7
#define NROI 512
#define NCH 256
#define BINS (NOUT * NOUT)          // 49
#define ROI_ELEMS (NCH * BINS)      // 12544
#define CHB 4                       // channels per block (8->4: double resident blocks)
#define NCG (NCH / CHB)             // 64 channel-groups per roi
#define OUTS (CHB * BINS)           // 196 outputs per block
// Worst-case footprint: level selection bounds feature-area fw*fh < 784 with
// fw,fh <= 124; discrete max of rs*(cs|1) over that set is 1062 floats
// (fh=124, fw=6.3 skew). 1091 > 1062 is sufficient; 1091 % 32 == 3 de-aligns
// per-channel bank bases (1088 was ≡0 mod 32 -> cross-channel conflicts).
#define TILE_STRIDE 1091
#define NIT ((TILE_STRIDE + 255) / 256)   // 5 staging issues per channel

__global__ __launch_bounds__(256, 8) void roi_pool_kernel(
    const float* __restrict__ x2,
    const float* __restrict__ x3,
    const float* __restrict__ x4,
    const float* __restrict__ x5,
    const float* __restrict__ boxes,
    float* __restrict__ out)
{
    const int r  = blockIdx.x;   // roi 0..511
    const int cg = blockIdx.y;   // channel group 0..63
    const int t  = threadIdx.x;  // 0..255

    // per-channel compact footprint tiles (runtime stride forced odd -> no
    // row-stride bank aliasing on the ds_read taps)
    __shared__ float tile[CHB][TILE_STRIDE];
    // per-ph: sdyA = {asint(rowoff_a), asint(rowoff_b), 0.25*va*(1-fya), 0.25*va*fya}
    //         sdyB = {0.25*vb*(1-fyb), 0.25*vb*fyb}   (rowoff = (i0 - ylo)*stride)
    // per-pw: sdxA = {asint(coloff_a), asint(coloff_b), va*(1-fxa), va*fxa}
    //         sdxB = {vb*(1-fxb), vb*fxb}             (coloff = i0 - xlo)
    __shared__ float4 sdyA[NOUT];
    __shared__ float2 sdyB[NOUT];
    __shared__ float4 sdxA[NOUT];
    __shared__ float2 sdxB[NOUT];
    __shared__ const float* s_src;  // feat + (b*NCH + cg*CHB)*HW + ylo*W + xlo
    __shared__ int s_W, s_HW, s_st, s_cs, s_pad;
    __shared__ unsigned s_M;        // ceil(2^32 / stride) for e -> row decomposition

    if (t < 32) {
        const float bx1 = boxes[4 * r + 0];
        const float by1 = boxes[4 * r + 1];
        const float bx2 = boxes[4 * r + 2];
        const float by2 = boxes[4 * r + 3];
        const float sz  = sqrtf((bx2 - bx1) * (by2 - by1));
        float lvlf = floorf(4.0f + log2f(sz / 224.0f + 1e-8f));
        lvlf = fminf(fmaxf(lvlf, 2.0f), 5.0f);
        const int level = (int)lvlf - 2;

        int H, W; float scale; const float* feat;
        if (level == 0)      { H = 200; W = 304; scale = 0.25f;    feat = x2; }
        else if (level == 1) { H = 100; W = 152; scale = 0.125f;   feat = x3; }
        else if (level == 2) { H = 50;  W = 76;  scale = 0.0625f;  feat = x4; }
        else                 { H = 25;  W = 38;  scale = 0.03125f; feat = x5; }

        const float X1 = bx1 * scale - 0.5f;
        const float Y1 = by1 * scale - 0.5f;
        const float X2 = bx2 * scale - 0.5f;
        const float Y2 = by2 * scale - 0.5f;
        const float bw = (X2 - X1) * (1.0f / NOUT);
        const float bh = (Y2 - Y1) * (1.0f / NOUT);

        // lanes 0..6: y-descriptors for ph = t; lanes 8..14: x-descriptors for
        // pw = t-8. All 32 lanes compute so the __shfl sources are valid.
        const bool isy = (t < 8);
        const int p    = min(isy ? t : (t - 8), 6);
        const int dim  = isy ? H : W;
        const float o0  = isy ? Y1 : X1;
        const float bsz = isy ? bh : bw;
        float ca = o0 + ((float)p + 0.25f) * bsz;
        float cb = o0 + ((float)p + 0.75f) * bsz;
        const float va = ((ca >= -1.0f) && (ca <= (float)dim)) ? 1.0f : 0.0f;
        const float vb = ((cb >= -1.0f) && (cb <= (float)dim)) ? 1.0f : 0.0f;
        ca = fminf(fmaxf(ca, 0.0f), (float)(dim - 1));
        cb = fminf(fmaxf(cb, 0.0f), (float)(dim - 1));
        const int ia = min((int)floorf(ca), dim - 2);   // taps ia, ia+1
        const int ib = min((int)floorf(cb), dim - 2);
        const float fa = ca - (float)ia;
        const float fb = cb - (float)ib;

        // footprint extents (sample positions are monotonic in p)
        const int ylo = __shfl(ia, 0);
        const int yhi = __shfl(ib, 6);
        const int xlo = __shfl(ia, 8);
        const int xhi = __shfl(ib, 14);
        const int cs = xhi + 2 - xlo;   // cols incl. +1 tap
        const int rs = yhi + 2 - ylo;   // rows incl. +1 tap
        const int st = cs | 1;          // odd LDS stride

        if (isy && t < 7) {
            sdyA[p] = make_float4(__int_as_float((ia - ylo) * st),
                                  __int_as_float((ib - ylo) * st),
                                  0.25f * va * (1.0f - fa), 0.25f * va * fa);
            sdyB[p] = make_float2(0.25f * vb * (1.0f - fb), 0.25f * vb * fb);
        } else if (!isy && t < 15) {
            sdxA[p] = make_float4(__int_as_float(ia - xlo),
                                  __int_as_float(ib - xlo),
                                  va * (1.0f - fa), va * fa);
            sdxB[p] = make_float2(vb * (1.0f - fb), vb * fb);
        } else if (t == 31) {
            const int HW = H * W;
            s_W   = W;
            s_HW  = HW;
            s_st  = st;
            s_cs  = cs;
            s_pad = min(rs * st, TILE_STRIDE);  // bound proven: rs*st <= 1062
            s_M   = (unsigned)(((1ull << 32) + (unsigned)st - 1) / (unsigned)st);
            s_src = feat + ((size_t)(r >> 8) * NCH + (size_t)cg * CHB) * HW
                         + (size_t)ylo * W + xlo;
        }
    }
    __syncthreads();

    // ---- stage: async global->LDS (fire-and-forget), one drain at barrier ----
    // All issues in flight simultaneously; coalesced wave segments (minimal
    // TA line-splits, unlike the gather kernels). LDS dest is wave-uniform
    // base + lane*4; global src is per-lane.
    {
        const int W   = s_W;
        const int st  = s_st;
        const int cs  = s_cs;
        const int pad = s_pad;
        const unsigned M = s_M;
        const int HW  = s_HW;
        const float* gsrc0 = s_src;
        const int wbase = t & 192;          // wave-uniform (0,64,128,192)
        const int lde   = t;                // lane's element slot = ebase + t
        #pragma unroll
        for (int ch = 0; ch < CHB; ++ch) {
            const float* gsrc = gsrc0 + (size_t)ch * HW;
            #pragma unroll
            for (int it = 0; it < NIT; ++it) {
                const int ebase = it * 256;
                const int e   = ebase + lde;
                const int row = (int)__umulhi((unsigned)e, M);  // e / st
                const int col = e - row * st;
                // col==cs only on the odd-pad column; never read -> skip
                // (stale LDS there is harmless). e>=pad slots never read.
                if (e < pad && col < cs) {
                    __builtin_amdgcn_global_load_lds(
                        (const __attribute__((address_space(1))) void*)
                            (gsrc + row * W + col),
                        (__attribute__((address_space(3))) void*)
                            (&tile[ch][ebase + wbase]),
                        4, 0, 0);
                }
            }
        }
    }
    __syncthreads();   // compiler emits vmcnt(0) drain before the barrier

    // ---- compute: 196 outputs per block from LDS (R2/R7-verified) ----
    const int st = s_st;
    float* const obase = out + (size_t)r * ROI_ELEMS + (size_t)cg * OUTS;
    for (int o = t; o < OUTS; o += 256) {
        const int cl  = o / BINS;
        const int bin = o - cl * BINS;
        const int ph  = bin / NOUT;
        const int pw  = bin - ph * NOUT;

        const float4 yA = sdyA[ph];
        const float2 yB = sdyB[ph];
        const float4 xA = sdxA[pw];
        const float2 xB = sdxB[pw];
        const int ro0 = __float_as_int(yA.x);
        const int ro1 = __float_as_int(yA.y);
        const int co0 = __float_as_int(xA.x);
        const int co1 = __float_as_int(xA.y);

        const float* Ta = tile[cl] + ro0;   // row iya       (+st -> iya+1)
        const float* Tb = tile[cl] + ro1;   // row iyb       (+st -> iyb+1)
        const float d0 = Ta[co0] * xA.z + Ta[co0 + 1] * xA.w
                       + Ta[co1] * xB.x + Ta[co1 + 1] * xB.y;
        const float d1 = Ta[st + co0] * xA.z + Ta[st + co0 + 1] * xA.w
                       + Ta[st + co1] * xB.x + Ta[st + co1 + 1] * xB.y;
        const float d2 = Tb[co0] * xA.z + Tb[co0 + 1] * xA.w
                       + Tb[co1] * xB.x + Tb[co1 + 1] * xB.y;
        const float d3 = Tb[st + co0] * xA.z + Tb[st + co0 + 1] * xA.w
                       + Tb[st + co1] * xB.x + Tb[st + co1 + 1] * xB.y;

        obase[o] = yA.z * d0 + yA.w * d1 + yB.x * d2 + yB.y * d3;
    }
}

extern "C" void kernel_launch(void* const* d_in, const int* in_sizes, int n_in,
                              void* d_out, int out_size, void* d_ws, size_t ws_size,
                              hipStream_t stream) {
    const float* x2    = (const float*)d_in[0];
    const float* x3    = (const float*)d_in[1];
    const float* x4    = (const float*)d_in[2];
    const float* x5    = (const float*)d_in[3];
    const float* boxes = (const float*)d_in[4];
    float* out = (float*)d_out;

    dim3 grid(NROI, NCG);
    roi_pool_kernel<<<grid, 256, 0, stream>>>(x2, x3, x4, x5, boxes, out);
}